// Round 9
// baseline (622.753 us; speedup 1.0000x reference)
//
#include <hip/hip_runtime.h>

#define B_    32
#define CIN_  64
#define COUT_ 64
#define IMG_  128
#define W4_   32                 // float4 per row
#define PIX4_ 4096               // float4 per plane
#define NPOS_ (B_ * PIX4_)       // 131072 float4 positions
#define NA_   512                // producer (A) blocks
#define DSTRIDE_ 64              // ints per done-slot (256 B, kills line contention)
#define DTARGET_ 16              // A-units per batch

// One kernel, two roles. Blocks [0,512): partial channel sums (R7's ch_sum2
// units) -> fence -> done[b]++. Blocks [512,4608): conv_shfl units that spin
// on done[b] then stream stores — overlapping A's HBM reads with B's writes.
// Bounded spin + recompute-from-x fallback makes it schedule-proof.
__global__ __launch_bounds__(256) void gc_fused_overlap(
    const float* __restrict__ x, const float* __restrict__ kern,
    const float* __restrict__ bias, float* __restrict__ out,
    float* __restrict__ part, int* __restrict__ done)
{
    const int n = blockIdx.x, tid = threadIdx.x;

    if (n < NA_) {
        // ---- A-unit: sum 32 channels over a 512-float4 chunk of batch b ----
        const int b = n >> 4, sub = n & 15, g = sub >> 3, q = sub & 7;
        const int p0 = q * 512 + tid, p1 = p0 + 256;
        const float4* xp = reinterpret_cast<const float4*>(x)
                         + ((size_t)b * CIN_ + (size_t)g * 32) * PIX4_;
        float4 a0 = make_float4(0.f,0.f,0.f,0.f), a1 = make_float4(0.f,0.f,0.f,0.f);
#pragma unroll 8
        for (int c = 0; c < 32; ++c) {
            float4 v0 = xp[(size_t)c * PIX4_ + p0];
            float4 v1 = xp[(size_t)c * PIX4_ + p1];
            a0.x += v0.x; a0.y += v0.y; a0.z += v0.z; a0.w += v0.w;
            a1.x += v1.x; a1.y += v1.y; a1.z += v1.z; a1.w += v1.w;
        }
        float4* pp = reinterpret_cast<float4*>(part)
                   + (size_t)g * NPOS_ + (size_t)b * PIX4_;
        pp[p0] = a0; pp[p1] = a1;
        __threadfence();                       // release stores, device scope
        __syncthreads();                       // whole block fenced
        if (tid == 0) atomicAdd(&done[b * DSTRIDE_], 1);
        return;
    }

    // ---- B-unit: (b, co, half-plane) conv via shfl halo ----
    const int v = n - NA_;                     // 0..4095, b ascending
    const int b = v >> 7, rest = v & 127, co = rest & 63, half = rest >> 6;
    const int w4 = tid & 31, rb = (tid >> 5) * 8, r0 = half * 64;

    __shared__ int s_fb;
    if (tid == 0) {
        int it = 0, fb = 0;
        while (__hip_atomic_load(&done[b * DSTRIDE_], __ATOMIC_ACQUIRE,
                                 __HIP_MEMORY_SCOPE_AGENT) < DTARGET_) {
            __builtin_amdgcn_s_sleep(15);
            if (++it > 50000) { fb = 1; break; }   // ~20 ms: never in practice
        }
        s_fb = fb;
    }
    __syncthreads();
    __threadfence();                           // acquire partials

    float4 C[10];
    if (s_fb == 0) {
        const float4* pb = reinterpret_cast<const float4*>(part) + (size_t)b * PIX4_;
#pragma unroll
        for (int r = 0; r < 10; ++r) {
            const int row = r0 + rb - 1 + r;
            float4 s = make_float4(0.f,0.f,0.f,0.f);
            if (row >= 0 && row < IMG_) {
                float4 u0 = pb[row * W4_ + w4];
                float4 u1 = pb[(size_t)NPOS_ + row * W4_ + w4];
                s = make_float4(u0.x+u1.x, u0.y+u1.y, u0.z+u1.z, u0.w+u1.w);
            }
            C[r] = s;
        }
    } else {
        // Fallback: recompute sums from x in the SAME fp order (g0-sum + g1-sum).
        const float4* xb = reinterpret_cast<const float4*>(x) + (size_t)b * CIN_ * PIX4_;
        for (int r = 0; r < 10; ++r) {
            const int row = r0 + rb - 1 + r;
            float4 s = make_float4(0.f,0.f,0.f,0.f);
            if (row >= 0 && row < IMG_) {
                float4 s0 = make_float4(0.f,0.f,0.f,0.f);
                float4 s1 = make_float4(0.f,0.f,0.f,0.f);
                for (int c = 0; c < 32; ++c) {
                    float4 u = xb[(size_t)c * PIX4_ + row * W4_ + w4];
                    s0.x += u.x; s0.y += u.y; s0.z += u.z; s0.w += u.w;
                }
                for (int c = 32; c < 64; ++c) {
                    float4 u = xb[(size_t)c * PIX4_ + row * W4_ + w4];
                    s1.x += u.x; s1.y += u.y; s1.z += u.z; s1.w += u.w;
                }
                s = make_float4(s0.x+s1.x, s0.y+s1.y, s0.z+s1.z, s0.w+s1.w);
            }
            C[r] = s;
        }
    }

    float Lw[10], Rx[10];
#pragma unroll
    for (int r = 0; r < 10; ++r) {
        float lw = __shfl_up(C[r].w, 1, 32);
        float rx = __shfl_down(C[r].x, 1, 32);
        Lw[r] = (w4 > 0)  ? lw : 0.f;
        Rx[r] = (w4 < 31) ? rx : 0.f;
    }

    const float* kw = kern + co * 9;
    const float k0 = kw[0], k1 = kw[1], k2 = kw[2];
    const float k3 = kw[3], k4 = kw[4], k5 = kw[5];
    const float k6 = kw[6], k7 = kw[7], k8 = kw[8];
    const float bv = (float)CIN_ * bias[co];

    float4* outp = reinterpret_cast<float4*>(out) + (size_t)(b * COUT_ + co) * PIX4_;

#pragma unroll
    for (int j = 0; j < 8; ++j) {
        float4 a;
        a.x = bv + k0 * Lw[j]     + k1 * C[j].x     + k2 * C[j].y
                 + k3 * Lw[j + 1] + k4 * C[j + 1].x + k5 * C[j + 1].y
                 + k6 * Lw[j + 2] + k7 * C[j + 2].x + k8 * C[j + 2].y;
        a.y = bv + k0 * C[j].x     + k1 * C[j].y     + k2 * C[j].z
                 + k3 * C[j + 1].x + k4 * C[j + 1].y + k5 * C[j + 1].z
                 + k6 * C[j + 2].x + k7 * C[j + 2].y + k8 * C[j + 2].z;
        a.z = bv + k0 * C[j].y     + k1 * C[j].z     + k2 * C[j].w
                 + k3 * C[j + 1].y + k4 * C[j + 1].z + k5 * C[j + 1].w
                 + k6 * C[j + 2].y + k7 * C[j + 2].z + k8 * C[j + 2].w;
        a.w = bv + k0 * C[j].z     + k1 * C[j].w     + k2 * Rx[j]
                 + k3 * C[j + 1].z + k4 * C[j + 1].w + k5 * Rx[j + 1]
                 + k6 * C[j + 2].z + k7 * C[j + 2].w + k8 * Rx[j + 2];
        outp[(size_t)(r0 + rb + j) * W4_ + w4] = a;
    }
}

extern "C" void kernel_launch(void* const* d_in, const int* in_sizes, int n_in,
                              void* d_out, int out_size, void* d_ws, size_t ws_size,
                              hipStream_t stream) {
    const float* x    = (const float*)d_in[0];   // (32,64,128,128) f32
    const float* kern = (const float*)d_in[1];   // (64,3,3) f32
    const float* bias = (const float*)d_in[2];   // (64,1,1,1) f32
    float* out  = (float*)d_out;                 // (32,64,128,128) f32
    float* part = (float*)d_ws;                  // 2 partial planes = 4 MiB
    int*   done = (int*)((char*)d_ws + 2u * NPOS_ * 16u);   // +4 MiB, 8 KiB

    hipMemsetAsync(done, 0, B_ * DSTRIDE_ * sizeof(int), stream);
    gc_fused_overlap<<<dim3(NA_ + B_ * COUT_ * 2), 256, 0, stream>>>(
        x, kern, bias, out, part, done);
}

// Round 10
// 60.960 us; speedup vs baseline: 10.2158x; 10.2158x over previous
//
#include <hip/hip_runtime.h>

#define B_    32
#define CIN_  64
#define COUT_ 64
#define IMG_  128
#define W4_   32                 // float4 per row
#define PIX4_ 4096               // float4 per plane
#define NPOS_ (B_ * PIX4_)       // 131072 float4 positions

typedef float f4v __attribute__((ext_vector_type(4)));

// ---- Kernel A: 2-group partial channel sums (512 blocks). x is L3-resident
// in steady state (out no longer evicts it — see nt stores in B). ----
__global__ __launch_bounds__(256) void ch_sum2(const float* __restrict__ x,
                                               float* __restrict__ part) {
    const int g   = blockIdx.y;                    // 0..1 channel group
    const int tid = threadIdx.x;
    const int i0  = blockIdx.x * 512 + tid;        // chunk of 512 float4
    const int i1  = i0 + 256;
    const int b   = i0 >> 12;
    const int p0  = i0 & (PIX4_ - 1);

    const float4* xp = reinterpret_cast<const float4*>(x)
                     + ((size_t)b * CIN_ + (size_t)g * 32) * PIX4_ + p0;

    float4 a0 = make_float4(0.f, 0.f, 0.f, 0.f);
    float4 a1 = make_float4(0.f, 0.f, 0.f, 0.f);
#pragma unroll 8
    for (int c = 0; c < 32; ++c) {
        float4 v0 = xp[(size_t)c * PIX4_];
        float4 v1 = xp[(size_t)c * PIX4_ + 256];
        a0.x += v0.x; a0.y += v0.y; a0.z += v0.z; a0.w += v0.w;
        a1.x += v1.x; a1.y += v1.y; a1.z += v1.z; a1.w += v1.w;
    }
    float4* pp = reinterpret_cast<float4*>(part) + (size_t)g * NPOS_;
    pp[i0] = a0;
    pp[i1] = a1;
}

// ---- Kernel B: no LDS. Block = (b, co, half-plane). Thread owns 8 rows at
// fixed w4; 10-row column loads from 2 L2/L3-resident partial planes, halo
// via shfl, 8 NONTEMPORAL float4 stores (bypass L3 -> out never squats). ----
__global__ __launch_bounds__(256) void conv_shfl(const float* __restrict__ part,
                                                 const float* __restrict__ kern,
                                                 const float* __restrict__ bias,
                                                 float* __restrict__ out) {
    const int n   = blockIdx.x;                    // 0..4095
    const int swz = (n & 7) * 512 + (n >> 3);      // bijective XCD chunking
    const int co   = swz & 63;
    const int half = (swz >> 6) & 1;
    const int b    = swz >> 7;
    const int tid  = threadIdx.x;
    const int w4   = tid & 31;
    const int rb   = (tid >> 5) * 8;               // local output rows rb..rb+7
    const int r0   = half * 64;

    const float4* p0 = reinterpret_cast<const float4*>(part) + (size_t)b * PIX4_;
    const float4* p1 = p0 + (size_t)NPOS_;

    float4 C[10];
#pragma unroll
    for (int r = 0; r < 10; ++r) {
        const int row = r0 + rb - 1 + r;
        float4 v = make_float4(0.f, 0.f, 0.f, 0.f);
        if (row >= 0 && row < IMG_) {
            float4 u0 = p0[row * W4_ + w4];
            float4 u1 = p1[row * W4_ + w4];
            v = make_float4(u0.x + u1.x, u0.y + u1.y, u0.z + u1.z, u0.w + u1.w);
        }
        C[r] = v;
    }

    float Lw[10], Rx[10];
#pragma unroll
    for (int r = 0; r < 10; ++r) {
        float lw = __shfl_up(C[r].w, 1, 32);
        float rx = __shfl_down(C[r].x, 1, 32);
        Lw[r] = (w4 > 0)  ? lw : 0.f;
        Rx[r] = (w4 < 31) ? rx : 0.f;
    }

    const float* kw = kern + co * 9;
    const float k0 = kw[0], k1 = kw[1], k2 = kw[2];
    const float k3 = kw[3], k4 = kw[4], k5 = kw[5];
    const float k6 = kw[6], k7 = kw[7], k8 = kw[8];
    const float bv = (float)CIN_ * bias[co];

    f4v* outp = reinterpret_cast<f4v*>(out) + (size_t)(b * COUT_ + co) * PIX4_;

#pragma unroll
    for (int j = 0; j < 8; ++j) {                  // rows j, j+1, j+2 of C
        float4 a;
        a.x = bv + k0 * Lw[j]     + k1 * C[j].x     + k2 * C[j].y
                 + k3 * Lw[j + 1] + k4 * C[j + 1].x + k5 * C[j + 1].y
                 + k6 * Lw[j + 2] + k7 * C[j + 2].x + k8 * C[j + 2].y;
        a.y = bv + k0 * C[j].x     + k1 * C[j].y     + k2 * C[j].z
                 + k3 * C[j + 1].x + k4 * C[j + 1].y + k5 * C[j + 1].z
                 + k6 * C[j + 2].x + k7 * C[j + 2].y + k8 * C[j + 2].z;
        a.z = bv + k0 * C[j].y     + k1 * C[j].z     + k2 * C[j].w
                 + k3 * C[j + 1].y + k4 * C[j + 1].z + k5 * C[j + 1].w
                 + k6 * C[j + 2].y + k7 * C[j + 2].z + k8 * C[j + 2].w;
        a.w = bv + k0 * C[j].z     + k1 * C[j].w     + k2 * Rx[j]
                 + k3 * C[j + 1].z + k4 * C[j + 1].w + k5 * Rx[j + 1]
                 + k6 * C[j + 2].z + k7 * C[j + 2].w + k8 * Rx[j + 2];

        f4v av; av.x = a.x; av.y = a.y; av.z = a.z; av.w = a.w;
        __builtin_nontemporal_store(av, &outp[(size_t)(r0 + rb + j) * W4_ + w4]);
    }
}

extern "C" void kernel_launch(void* const* d_in, const int* in_sizes, int n_in,
                              void* d_out, int out_size, void* d_ws, size_t ws_size,
                              hipStream_t stream) {
    const float* x    = (const float*)d_in[0];   // (32,64,128,128) f32
    const float* kern = (const float*)d_in[1];   // (64,3,3) f32
    const float* bias = (const float*)d_in[2];   // (64,1,1,1) f32
    float* out  = (float*)d_out;                 // (32,64,128,128) f32
    float* part = (float*)d_ws;                  // 2 x 2 MiB partial planes

    dim3 ga(NPOS_ / 512, 2);                     // (256, 2) = 512 blocks
    ch_sum2<<<ga, 256, 0, stream>>>(x, part);

    conv_shfl<<<dim3(B_ * COUT_ * 2), 256, 0, stream>>>(part, kern, bias, out);
}